// Round 1
// baseline (2828.115 us; speedup 1.0000x reference)
//
#include <hip/hip_runtime.h>

typedef unsigned short u16;
typedef unsigned int u32;
typedef __attribute__((ext_vector_type(8))) __bf16 bf16x8;
typedef __attribute__((ext_vector_type(4))) float f32x4;

#define B_ 64
#define S_ 256
#define OBS_ 96
#define ACT_ 29
#define D_ 512
#define H_ 8
#define L_ 8
#define FF_ 2048
#define HD_ 64
#define NTOK (B_ * S_)   // 16384

__device__ __forceinline__ u16 f2bf(float f) {
    u32 u = __float_as_uint(f);
    u += 0x7FFFu + ((u >> 16) & 1u);
    return (u16)(u >> 16);
}
__device__ __forceinline__ float bf2f(u16 h) {
    return __uint_as_float(((u32)h) << 16);
}
__device__ __forceinline__ float gelu_f(float x) {
    return 0.5f * x * (1.0f + erff(x * 0.70710678118654752f));
}

// ---------------------------------------------------------------------------
// Transpose + downcast: src fp32 [batch][K][N] -> dst bf16 [batch][N][K]
// ---------------------------------------------------------------------------
__global__ __launch_bounds__(256) void transpose_bf16_kernel(
    const float* __restrict__ src, u16* __restrict__ dst, int K, int N)
{
    __shared__ float tile[32][33];
    int n0 = blockIdx.x * 32, k0 = blockIdx.y * 32;
    const float* s = src + (size_t)blockIdx.z * K * N;
    u16* d = dst + (size_t)blockIdx.z * K * N;
    int tx = threadIdx.x, ty = threadIdx.y;   // block (32,8)
    for (int i = 0; i < 32; i += 8)
        tile[ty + i][tx] = s[(size_t)(k0 + ty + i) * N + n0 + tx];
    __syncthreads();
    for (int i = 0; i < 32; i += 8)
        d[(size_t)(n0 + ty + i) * K + k0 + tx] = f2bf(tile[tx][ty + i]);
}

// ---------------------------------------------------------------------------
// Input projection: x = gelu(LN(obs @ W_in + b_in)) + PE  -> bf16 [NTOK][512]
// one token per block, 256 threads
// ---------------------------------------------------------------------------
__global__ __launch_bounds__(256) void input_proj_kernel(
    const float* __restrict__ obs, const float* __restrict__ Win,
    const float* __restrict__ b_in, const float* __restrict__ g_in,
    const float* __restrict__ be_in, u16* __restrict__ xout)
{
    __shared__ float ob[OBS_];
    __shared__ float rs[4], rq[4];
    int row = blockIdx.x;       // token index
    int s = row & (S_ - 1);     // seq position
    int t = threadIdx.x;
    if (t < OBS_) ob[t] = obs[(size_t)row * OBS_ + t];
    __syncthreads();
    float acc0 = b_in[t], acc1 = b_in[t + 256];
    for (int kk = 0; kk < OBS_; kk++) {
        float o = ob[kk];
        acc0 += o * Win[kk * D_ + t];
        acc1 += o * Win[kk * D_ + t + 256];
    }
    float sm = acc0 + acc1, sq = acc0 * acc0 + acc1 * acc1;
    for (int off = 32; off; off >>= 1) {
        sm += __shfl_xor(sm, off);
        sq += __shfl_xor(sq, off);
    }
    if ((t & 63) == 0) { rs[t >> 6] = sm; rq[t >> 6] = sq; }
    __syncthreads();
    float ts = rs[0] + rs[1] + rs[2] + rs[3];
    float tq = rq[0] + rq[1] + rq[2] + rq[3];
    float mean = ts / (float)D_;
    float var = tq / (float)D_ - mean * mean;
    float rstd = rsqrtf(var + 1e-5f);
    const float c = -9.210340371976184f / (float)D_;  // -ln(10000)/D
    #pragma unroll
    for (int half = 0; half < 2; half++) {
        int n = t + half * 256;
        float v = half ? acc1 : acc0;
        float y = (v - mean) * rstd * g_in[n] + be_in[n];
        y = gelu_f(y);
        int i = n >> 1;
        float ang = (float)s * __expf((float)(2 * i) * c);
        y += (n & 1) ? __cosf(ang) : __sinf(ang);
        xout[(size_t)row * D_ + n] = f2bf(y);
    }
}

// ---------------------------------------------------------------------------
// GEMM: C[M][N] = A[M][K](bf16) @ B[K][N] + bias,  B given transposed BT[N][K]
// EPI: 0 = bf16 out, 1 = bf16 out with GELU, 2 = fp32 out
// block 256 threads (4 waves, 2x2), tile 128x128, BK=32
// ---------------------------------------------------------------------------
template <int EPI>
__global__ __launch_bounds__(256) void gemm_bt_kernel(
    const u16* __restrict__ A, const u16* __restrict__ BT,
    const float* __restrict__ bias, void* __restrict__ C,
    int M, int N, int K)
{
    __shared__ __align__(16) u16 As[128 * 32];
    __shared__ __align__(16) u16 Bs[128 * 32];
    int m0 = blockIdx.y * 128, n0 = blockIdx.x * 128;
    int t = threadIdx.x;
    int lane = t & 63, w = t >> 6;
    int wm = w >> 1, wn = w & 1;
    int l15 = lane & 15, quad = lane >> 4;

    f32x4 acc[4][4];
    f32x4 zero = {0.f, 0.f, 0.f, 0.f};
    #pragma unroll
    for (int mi = 0; mi < 4; mi++)
        #pragma unroll
        for (int ni = 0; ni < 4; ni++) acc[mi][ni] = zero;

    for (int k0 = 0; k0 < K; k0 += 32) {
        __syncthreads();
        #pragma unroll
        for (int i = 0; i < 2; i++) {
            int ci = t + i * 256;            // chunk id 0..511 (16B chunks)
            int r = ci >> 2, cc = ci & 3;
            *(uint4*)&As[ci * 8] =
                *(const uint4*)(A + (size_t)(m0 + r) * K + k0 + cc * 8);
            *(uint4*)&Bs[ci * 8] =
                *(const uint4*)(BT + (size_t)(n0 + r) * K + k0 + cc * 8);
        }
        __syncthreads();
        bf16x8 a[4], b[4];
        #pragma unroll
        for (int mi = 0; mi < 4; mi++)
            a[mi] = *(const bf16x8*)&As[(wm * 64 + mi * 16 + l15) * 32 + quad * 8];
        #pragma unroll
        for (int ni = 0; ni < 4; ni++)
            b[ni] = *(const bf16x8*)&Bs[(wn * 64 + ni * 16 + l15) * 32 + quad * 8];
        #pragma unroll
        for (int mi = 0; mi < 4; mi++)
            #pragma unroll
            for (int ni = 0; ni < 4; ni++)
                acc[mi][ni] = __builtin_amdgcn_mfma_f32_16x16x32_bf16(
                    a[mi], b[ni], acc[mi][ni], 0, 0, 0);
    }

    #pragma unroll
    for (int ni = 0; ni < 4; ni++) {
        int col = n0 + wn * 64 + ni * 16 + l15;
        float bv = bias[col];
        #pragma unroll
        for (int mi = 0; mi < 4; mi++) {
            int rbase = m0 + wm * 64 + mi * 16 + quad * 4;
            f32x4 v = acc[mi][ni];
            #pragma unroll
            for (int r = 0; r < 4; r++) {
                float y = v[r] + bv;
                if (EPI == 1) y = gelu_f(y);
                size_t idx = (size_t)(rbase + r) * N + col;
                if (EPI == 2) ((float*)C)[idx] = y;
                else          ((u16*)C)[idx] = f2bf(y);
            }
        }
    }
}

// ---------------------------------------------------------------------------
// Attention: per block = one (b, h, 64-q-row chunk). 256 threads, 4 waves.
// q,k,v,o: bf16 [NTOK][512], head h at cols h*64..h*64+63
// ---------------------------------------------------------------------------
__global__ __launch_bounds__(256) void attn_kernel(
    const u16* __restrict__ q, const u16* __restrict__ k,
    const u16* __restrict__ v, u16* __restrict__ o)
{
    __shared__ __align__(16) u16 kvs[S_ * HD_];      // 32 KB: K rows, then V^T
    __shared__ __align__(16) u16 P[4 * 16 * S_];     // 32 KB: per-wave probs
    int bx = blockIdx.x;
    int qc = bx & 3;
    int h = (bx >> 2) & 7;
    int b = bx >> 5;
    int t = threadIdx.x;
    int lane = t & 63, w = t >> 6;
    int l15 = lane & 15, quad = lane >> 4;
    size_t base_bh = ((size_t)b * S_) * D_ + h * HD_;

    // stage K: thread t loads K row s=t (64 bf16)
    {
        const u16* src = k + base_bh + (size_t)t * D_;
        #pragma unroll
        for (int j = 0; j < 8; j++)
            *(uint4*)&kvs[t * HD_ + j * 8] = *(const uint4*)(src + j * 8);
    }
    // load Q fragments (wave's 16 q rows)
    bf16x8 aQ[2];
    {
        int qrow = qc * 64 + w * 16 + l15;
        const u16* src = q + base_bh + (size_t)qrow * D_ + quad * 8;
        aQ[0] = *(const bf16x8*)(src);
        aQ[1] = *(const bf16x8*)(src + 32);
    }
    __syncthreads();

    // phase 1: S = Q K^T  (wave computes 16 x 256)
    f32x4 sc[16];
    #pragma unroll
    for (int nc = 0; nc < 16; nc++) {
        f32x4 acc = {0.f, 0.f, 0.f, 0.f};
        bf16x8 b0 = *(const bf16x8*)&kvs[(nc * 16 + l15) * HD_ + quad * 8];
        bf16x8 b1 = *(const bf16x8*)&kvs[(nc * 16 + l15) * HD_ + 32 + quad * 8];
        acc = __builtin_amdgcn_mfma_f32_16x16x32_bf16(aQ[0], b0, acc, 0, 0, 0);
        acc = __builtin_amdgcn_mfma_f32_16x16x32_bf16(aQ[1], b1, acc, 0, 0, 0);
        sc[nc] = acc;
    }
    const float scale = 0.125f;  // 1/sqrt(64)
    float rmax[4], rinv[4];
    #pragma unroll
    for (int r = 0; r < 4; r++) {
        float mx = -1e30f;
        #pragma unroll
        for (int nc = 0; nc < 16; nc++) mx = fmaxf(mx, sc[nc][r]);
        for (int off = 1; off < 16; off <<= 1) mx = fmaxf(mx, __shfl_xor(mx, off));
        rmax[r] = mx * scale;
    }
    #pragma unroll
    for (int r = 0; r < 4; r++) {
        float sum = 0.f;
        #pragma unroll
        for (int nc = 0; nc < 16; nc++) {
            float p = __expf(sc[nc][r] * scale - rmax[r]);
            sc[nc][r] = p;
            sum += p;
        }
        for (int off = 1; off < 16; off <<= 1) sum += __shfl_xor(sum, off);
        rinv[r] = 1.0f / sum;
    }
    #pragma unroll
    for (int nc = 0; nc < 16; nc++)
        #pragma unroll
        for (int r = 0; r < 4; r++)
            P[w * 16 * S_ + (quad * 4 + r) * S_ + nc * 16 + l15] =
                f2bf(sc[nc][r] * rinv[r]);
    __syncthreads();  // all waves done with K region + P written

    // stage V^T[64][256] into kvs
    {
        const u16* src = v + base_bh + (size_t)t * D_;
        #pragma unroll
        for (int dj = 0; dj < 8; dj++) {
            uint4 x = *(const uint4*)(src + dj * 8);
            const u16* xs = (const u16*)&x;
            #pragma unroll
            for (int i = 0; i < 8; i++) kvs[(dj * 8 + i) * S_ + t] = xs[i];
        }
    }
    __syncthreads();

    // phase 2: O = P @ V   (wave: 16 x 64)
    f32x4 accO[4];
    f32x4 zero = {0.f, 0.f, 0.f, 0.f};
    #pragma unroll
    for (int nt = 0; nt < 4; nt++) accO[nt] = zero;
    for (int ks = 0; ks < 8; ks++) {
        bf16x8 aP = *(const bf16x8*)&P[w * 16 * S_ + l15 * S_ + ks * 32 + quad * 8];
        #pragma unroll
        for (int nt = 0; nt < 4; nt++) {
            bf16x8 bV = *(const bf16x8*)&kvs[(nt * 16 + l15) * S_ + ks * 32 + quad * 8];
            accO[nt] = __builtin_amdgcn_mfma_f32_16x16x32_bf16(aP, bV, accO[nt], 0, 0, 0);
        }
    }
    #pragma unroll
    for (int nt = 0; nt < 4; nt++)
        #pragma unroll
        for (int r = 0; r < 4; r++) {
            int orow = qc * 64 + w * 16 + quad * 4 + r;
            o[base_bh + (size_t)orow * D_ + nt * 16 + l15] = f2bf(accO[nt][r]);
        }
}

// ---------------------------------------------------------------------------
// LayerNorm: out = LN(in [+ res]) * g + b, optional GELU. One row per block.
// in fp32 [M][WIDTH], res bf16 (or null), out bf16
// ---------------------------------------------------------------------------
template <int WIDTH, bool RES, bool GELU>
__global__ __launch_bounds__(WIDTH) void ln_kernel(
    const float* __restrict__ in, const u16* __restrict__ res,
    const float* __restrict__ g, const float* __restrict__ b,
    u16* __restrict__ out)
{
    __shared__ float rs[8], rq[8];
    int row = blockIdx.x;
    int t = threadIdx.x;
    size_t base = (size_t)row * WIDTH;
    float v = in[base + t];
    if (RES) v += bf2f(res[base + t]);
    float sm = v, sq = v * v;
    for (int off = 32; off; off >>= 1) {
        sm += __shfl_xor(sm, off);
        sq += __shfl_xor(sq, off);
    }
    constexpr int NW = WIDTH / 64;
    if ((t & 63) == 0) { rs[t >> 6] = sm; rq[t >> 6] = sq; }
    __syncthreads();
    float ts = 0.f, tq = 0.f;
    #pragma unroll
    for (int i = 0; i < NW; i++) { ts += rs[i]; tq += rq[i]; }
    float mean = ts / (float)WIDTH;
    float var = tq / (float)WIDTH - mean * mean;
    float rstd = rsqrtf(var + 1e-5f);
    float y = (v - mean) * rstd * g[t] + b[t];
    if (GELU) y = gelu_f(y);
    out[base + t] = f2bf(y);
}

// ---------------------------------------------------------------------------
// Head: out = tanh(y2 @ Wp3 + bp3) * scale + bias. 8 rows x 32 cols per block.
// ---------------------------------------------------------------------------
__global__ __launch_bounds__(256) void head_kernel(
    const u16* __restrict__ y2, const float* __restrict__ W,
    const float* __restrict__ bias, const float* __restrict__ scl,
    const float* __restrict__ bs, float* __restrict__ out)
{
    __shared__ float Ws[128 * ACT_];
    __shared__ u16 Ys[8 * 128];
    int t = threadIdx.x;
    for (int i = t; i < 128 * ACT_; i += 256) Ws[i] = W[i];
    int r0 = blockIdx.x * 8;
    for (int i = t; i < 8 * 128; i += 256) Ys[i] = y2[(size_t)r0 * 128 + i];
    __syncthreads();
    int lr = t >> 5, c = t & 31;
    if (c < ACT_) {
        float acc = bias[c];
        for (int kk = 0; kk < 128; kk++)
            acc += bf2f(Ys[lr * 128 + kk]) * Ws[kk * ACT_ + c];
        float y = tanhf(acc);
        out[(size_t)(r0 + lr) * ACT_ + c] = y * scl[c] + bs[c];
    }
}

// ---------------------------------------------------------------------------
extern "C" void kernel_launch(void* const* d_in, const int* in_sizes, int n_in,
                              void* d_out, int out_size, void* d_ws, size_t ws_size,
                              hipStream_t stream)
{
    const float* obs   = (const float*)d_in[0];
    const float* W_in  = (const float*)d_in[1];
    const float* b_in  = (const float*)d_in[2];
    const float* g_in  = (const float*)d_in[3];
    const float* be_in = (const float*)d_in[4];
    const float* Wq  = (const float*)d_in[5];
    const float* bq  = (const float*)d_in[6];
    const float* Wk  = (const float*)d_in[7];
    const float* bk  = (const float*)d_in[8];
    const float* Wv  = (const float*)d_in[9];
    const float* bv  = (const float*)d_in[10];
    const float* Wo  = (const float*)d_in[11];
    const float* bo  = (const float*)d_in[12];
    const float* g1  = (const float*)d_in[13];
    const float* be1 = (const float*)d_in[14];
    const float* W1  = (const float*)d_in[15];
    const float* b1  = (const float*)d_in[16];
    const float* W2  = (const float*)d_in[17];
    const float* b2  = (const float*)d_in[18];
    const float* g2  = (const float*)d_in[19];
    const float* be2 = (const float*)d_in[20];
    const float* Wp1  = (const float*)d_in[21];
    const float* bp1  = (const float*)d_in[22];
    const float* gp1  = (const float*)d_in[23];
    const float* bep1 = (const float*)d_in[24];
    const float* Wp2  = (const float*)d_in[25];
    const float* bp2  = (const float*)d_in[26];
    const float* gp2  = (const float*)d_in[27];
    const float* bep2 = (const float*)d_in[28];
    const float* Wp3  = (const float*)d_in[29];
    const float* bp3  = (const float*)d_in[30];
    const float* ascl = (const float*)d_in[31];
    const float* abias = (const float*)d_in[32];

    char* ws = (char*)d_ws;
    size_t off = 0;
    auto alloc = [&](size_t bytes) {
        void* p = ws + off;
        off += (bytes + 255) & ~(size_t)255;
        return p;
    };
    u16* WQT  = (u16*)alloc((size_t)L_ * D_ * D_ * 2);
    u16* WKT  = (u16*)alloc((size_t)L_ * D_ * D_ * 2);
    u16* WVT  = (u16*)alloc((size_t)L_ * D_ * D_ * 2);
    u16* WOT  = (u16*)alloc((size_t)L_ * D_ * D_ * 2);
    u16* W1T  = (u16*)alloc((size_t)L_ * D_ * FF_ * 2);
    u16* W2T  = (u16*)alloc((size_t)L_ * FF_ * D_ * 2);
    u16* WP1T = (u16*)alloc((size_t)D_ * (D_ / 2) * 2);
    u16* WP2T = (u16*)alloc((size_t)(D_ / 2) * (D_ / 4) * 2);
    u16* x_bf = (u16*)alloc((size_t)NTOK * D_ * 2);
    float* tmp = (float*)alloc((size_t)NTOK * D_ * 4);        // 32 MB, multi-use
    char* regionA = (char*)alloc((size_t)NTOK * FF_ * 2);     // 64 MB
    (void)ws_size; (void)in_sizes; (void)n_in; (void)out_size;

    u16* qbuf = (u16*)(regionA);
    u16* kbuf = (u16*)(regionA + (size_t)NTOK * D_ * 2);
    u16* vbuf = (u16*)(regionA + (size_t)NTOK * D_ * 2 * 2);
    u16* obuf = (u16*)(regionA + (size_t)NTOK * D_ * 2 * 3);
    u16* hbuf = (u16*)(regionA);
    // head-stage aliases inside tmp (32 MB)
    char* tmpB = (char*)tmp;
    float* p1out = tmp;                              // [NTOK][256] f32, 16 MB
    u16* y1_bf = (u16*)(tmpB + (16u << 20));         // 8 MB
    float* p2out = (float*)(tmpB + (24u << 20));     // [NTOK][128] f32, 8 MB
    u16* y2_bf = (u16*)(tmpB);                       // 4 MB (p1out dead)

    dim3 tb(32, 8);
    transpose_bf16_kernel<<<dim3(16, 16, L_), tb, 0, stream>>>(Wq, WQT, D_, D_);
    transpose_bf16_kernel<<<dim3(16, 16, L_), tb, 0, stream>>>(Wk, WKT, D_, D_);
    transpose_bf16_kernel<<<dim3(16, 16, L_), tb, 0, stream>>>(Wv, WVT, D_, D_);
    transpose_bf16_kernel<<<dim3(16, 16, L_), tb, 0, stream>>>(Wo, WOT, D_, D_);
    transpose_bf16_kernel<<<dim3(64, 16, L_), tb, 0, stream>>>(W1, W1T, D_, FF_);
    transpose_bf16_kernel<<<dim3(16, 64, L_), tb, 0, stream>>>(W2, W2T, FF_, D_);
    transpose_bf16_kernel<<<dim3(8, 16, 1),  tb, 0, stream>>>(Wp1, WP1T, D_, D_ / 2);
    transpose_bf16_kernel<<<dim3(4, 8, 1),   tb, 0, stream>>>(Wp2, WP2T, D_ / 2, D_ / 4);

    input_proj_kernel<<<NTOK, 256, 0, stream>>>(obs, W_in, b_in, g_in, be_in, x_bf);

    const int MG = NTOK / 128;  // 128
    for (int l = 0; l < L_; l++) {
        const u16* wqt = WQT + (size_t)l * D_ * D_;
        const u16* wkt = WKT + (size_t)l * D_ * D_;
        const u16* wvt = WVT + (size_t)l * D_ * D_;
        const u16* wot = WOT + (size_t)l * D_ * D_;
        const u16* w1t = W1T + (size_t)l * D_ * FF_;
        const u16* w2t = W2T + (size_t)l * FF_ * D_;

        gemm_bt_kernel<0><<<dim3(D_ / 128, MG), 256, 0, stream>>>(
            x_bf, wqt, bq + l * D_, qbuf, NTOK, D_, D_);
        gemm_bt_kernel<0><<<dim3(D_ / 128, MG), 256, 0, stream>>>(
            x_bf, wkt, bk + l * D_, kbuf, NTOK, D_, D_);
        gemm_bt_kernel<0><<<dim3(D_ / 128, MG), 256, 0, stream>>>(
            x_bf, wvt, bv + l * D_, vbuf, NTOK, D_, D_);
        attn_kernel<<<B_ * H_ * (S_ / 64), 256, 0, stream>>>(qbuf, kbuf, vbuf, obuf);
        gemm_bt_kernel<2><<<dim3(D_ / 128, MG), 256, 0, stream>>>(
            obuf, wot, bo + l * D_, tmp, NTOK, D_, D_);
        ln_kernel<D_, true, false><<<NTOK, D_, 0, stream>>>(
            tmp, x_bf, g1 + l * D_, be1 + l * D_, x_bf);
        gemm_bt_kernel<1><<<dim3(FF_ / 128, MG), 256, 0, stream>>>(
            x_bf, w1t, b1 + l * FF_, hbuf, NTOK, FF_, D_);
        gemm_bt_kernel<2><<<dim3(D_ / 128, MG), 256, 0, stream>>>(
            hbuf, w2t, b2 + l * D_, tmp, NTOK, D_, FF_);
        ln_kernel<D_, true, false><<<NTOK, D_, 0, stream>>>(
            tmp, x_bf, g2 + l * D_, be2 + l * D_, x_bf);
    }

    // policy head
    gemm_bt_kernel<2><<<dim3((D_ / 2) / 128, MG), 256, 0, stream>>>(
        x_bf, WP1T, bp1, p1out, NTOK, D_ / 2, D_);
    ln_kernel<D_ / 2, false, true><<<NTOK, D_ / 2, 0, stream>>>(
        p1out, nullptr, gp1, bep1, y1_bf);
    gemm_bt_kernel<2><<<dim3((D_ / 4) / 128, MG), 256, 0, stream>>>(
        y1_bf, WP2T, bp2, p2out, NTOK, D_ / 4, D_ / 2);
    ln_kernel<D_ / 4, false, true><<<NTOK, D_ / 4, 0, stream>>>(
        p2out, nullptr, gp2, bep2, y2_bf);
    head_kernel<<<NTOK / 8, 256, 0, stream>>>(
        y2_bf, Wp3, bp3, ascl, abias, (float*)d_out);
}

// Round 2
// 2625.557 us; speedup vs baseline: 1.0771x; 1.0771x over previous
//
#include <hip/hip_runtime.h>

typedef unsigned short u16;
typedef unsigned int u32;
typedef __attribute__((ext_vector_type(8))) __bf16 bf16x8;
typedef __attribute__((ext_vector_type(4))) float f32x4;

#define B_ 64
#define S_ 256
#define OBS_ 96
#define ACT_ 29
#define D_ 512
#define H_ 8
#define L_ 8
#define FF_ 2048
#define HD_ 64
#define NTOK (B_ * S_)   // 16384
#define QKV3 (3 * D_)    // 1536

__device__ __forceinline__ u16 f2bf(float f) {
    u32 u = __float_as_uint(f);
    u += 0x7FFFu + ((u >> 16) & 1u);
    return (u16)(u >> 16);
}
__device__ __forceinline__ float bf2f(u16 h) {
    return __uint_as_float(((u32)h) << 16);
}
__device__ __forceinline__ float gelu_f(float x) {
    return 0.5f * x * (1.0f + erff(x * 0.70710678118654752f));
}
// async global->LDS, 16B per lane. LDS dest is wave-uniform base + lane*16.
__device__ __forceinline__ void gld_lds16(const u16* g, u16* l) {
    __builtin_amdgcn_global_load_lds(
        (const __attribute__((address_space(1))) unsigned int*)g,
        (__attribute__((address_space(3))) unsigned int*)l, 16, 0, 0);
}

// ---------------------------------------------------------------------------
// Transpose + downcast: src fp32 [z][K][N] -> dst bf16 [z][N][K] (strided)
// ---------------------------------------------------------------------------
__global__ __launch_bounds__(256) void transpose_bf16_kernel(
    const float* __restrict__ src, u16* __restrict__ dst, int K, int N,
    size_t srcStride, size_t dstStride)
{
    __shared__ float tile[32][33];
    int n0 = blockIdx.x * 32, k0 = blockIdx.y * 32;
    const float* s = src + (size_t)blockIdx.z * srcStride;
    u16* d = dst + (size_t)blockIdx.z * dstStride;
    int tx = threadIdx.x, ty = threadIdx.y;   // block (32,8)
    for (int i = 0; i < 32; i += 8)
        tile[ty + i][tx] = s[(size_t)(k0 + ty + i) * N + n0 + tx];
    __syncthreads();
    for (int i = 0; i < 32; i += 8)
        d[(size_t)(n0 + ty + i) * K + k0 + tx] = f2bf(tile[tx][ty + i]);
}

// ---------------------------------------------------------------------------
// Concat bias: bqkv[l][0:512)=bq[l], [512:1024)=bk[l], [1024:1536)=bv[l]
// ---------------------------------------------------------------------------
__global__ __launch_bounds__(256) void concat_bias_kernel(
    const float* __restrict__ bq, const float* __restrict__ bk,
    const float* __restrict__ bv, float* __restrict__ dst)
{
    int i = blockIdx.x * 256 + threadIdx.x;      // over L*1536
    int l = i / QKV3, r = i - l * QKV3;
    float v;
    if (r < D_)            v = bq[l * D_ + r];
    else if (r < 2 * D_)   v = bk[l * D_ + r - D_];
    else                   v = bv[l * D_ + r - 2 * D_];
    dst[i] = v;
}

// ---------------------------------------------------------------------------
// Input projection GEMM (full fp32): outp[M][512] = obs[M][96] @ Win[96][512] + b
// tile 64x64, whole K=96 staged. 256 threads, each 4x4 outputs.
// ---------------------------------------------------------------------------
__global__ __launch_bounds__(256) void in_gemm_kernel(
    const float* __restrict__ obs, const float* __restrict__ Win,
    const float* __restrict__ b_in, float* __restrict__ outp)
{
    __shared__ float As[OBS_][68];   // [k][m], stride 68 keeps float4 aligned
    __shared__ float Bs[OBS_][68];   // [k][n]
    int m0 = blockIdx.y * 64, n0 = blockIdx.x * 64;
    int t = threadIdx.x;
    #pragma unroll
    for (int i = 0; i < 24; i++) {               // 64*96 = 6144 = 24*256
        int idx = i * 256 + t;
        int m = idx / OBS_, kk = idx - m * OBS_;
        As[kk][m] = obs[(size_t)(m0 + m) * OBS_ + kk];
    }
    #pragma unroll
    for (int i = 0; i < 24; i++) {
        int idx = i * 256 + t;
        int kk = idx >> 6, n = idx & 63;
        Bs[kk][n] = Win[(size_t)kk * D_ + n0 + n];
    }
    __syncthreads();
    int tm = t >> 4, tn = t & 15;
    float acc[4][4] = {};
    for (int kk = 0; kk < OBS_; kk++) {
        float4 a = *(const float4*)&As[kk][tm * 4];
        float4 b = *(const float4*)&Bs[kk][tn * 4];
        const float av[4] = {a.x, a.y, a.z, a.w};
        const float bv[4] = {b.x, b.y, b.z, b.w};
        #pragma unroll
        for (int r = 0; r < 4; r++)
            #pragma unroll
            for (int c = 0; c < 4; c++) acc[r][c] += av[r] * bv[c];
    }
    #pragma unroll
    for (int r = 0; r < 4; r++)
        #pragma unroll
        for (int c = 0; c < 4; c++) {
            int col = n0 + tn * 4 + c;
            outp[(size_t)(m0 + tm * 4 + r) * D_ + col] = acc[r][c] + b_in[col];
        }
}

// ---------------------------------------------------------------------------
// GEMM: C[M][N] = A[M][K](bf16) @ BT[N][K](bf16) + bias
// EPI: 0 = bf16 out, 1 = bf16+GELU, 2 = fp32 out
// 256 threads (4 waves 2x2), tile 128x128, BK=32, global_load_lds staging
// ---------------------------------------------------------------------------
template <int EPI>
__global__ __launch_bounds__(256) void gemm_bt_kernel(
    const u16* __restrict__ A, const u16* __restrict__ BT,
    const float* __restrict__ bias, void* __restrict__ C,
    int M, int N, int K)
{
    __shared__ __align__(16) u16 As[128 * 32];
    __shared__ __align__(16) u16 Bs[128 * 32];
    int m0 = blockIdx.y * 128, n0 = blockIdx.x * 128;
    int t = threadIdx.x;
    int lane = t & 63, w = t >> 6;
    int wm = w >> 1, wn = w & 1;
    int l15 = lane & 15, quad = lane >> 4;

    f32x4 acc[4][4];
    f32x4 zero = {0.f, 0.f, 0.f, 0.f};
    #pragma unroll
    for (int mi = 0; mi < 4; mi++)
        #pragma unroll
        for (int ni = 0; ni < 4; ni++) acc[mi][ni] = zero;

    for (int k0 = 0; k0 < K; k0 += 32) {
        __syncthreads();
        #pragma unroll
        for (int i = 0; i < 2; i++) {
            int c0 = (w * 2 + i) * 64 + lane;    // 16B-chunk id, 0..511
            int r = c0 >> 2, cc = c0 & 3;
            gld_lds16(A  + (size_t)(m0 + r) * K + k0 + cc * 8, &As[c0 * 8]);
            gld_lds16(BT + (size_t)(n0 + r) * K + k0 + cc * 8, &Bs[c0 * 8]);
        }
        __syncthreads();                          // drains vmcnt before barrier
        bf16x8 a[4], b[4];
        #pragma unroll
        for (int mi = 0; mi < 4; mi++)
            a[mi] = *(const bf16x8*)&As[(wm * 64 + mi * 16 + l15) * 32 + quad * 8];
        #pragma unroll
        for (int ni = 0; ni < 4; ni++)
            b[ni] = *(const bf16x8*)&Bs[(wn * 64 + ni * 16 + l15) * 32 + quad * 8];
        #pragma unroll
        for (int mi = 0; mi < 4; mi++)
            #pragma unroll
            for (int ni = 0; ni < 4; ni++)
                acc[mi][ni] = __builtin_amdgcn_mfma_f32_16x16x32_bf16(
                    a[mi], b[ni], acc[mi][ni], 0, 0, 0);
    }

    #pragma unroll
    for (int ni = 0; ni < 4; ni++) {
        int col = n0 + wn * 64 + ni * 16 + l15;
        float bv = bias[col];
        #pragma unroll
        for (int mi = 0; mi < 4; mi++) {
            int rbase = m0 + wm * 64 + mi * 16 + quad * 4;
            f32x4 v = acc[mi][ni];
            #pragma unroll
            for (int r = 0; r < 4; r++) {
                float y = v[r] + bv;
                if (EPI == 1) y = gelu_f(y);
                size_t idx = (size_t)(rbase + r) * N + col;
                if (EPI == 2) ((float*)C)[idx] = y;
                else          ((u16*)C)[idx] = f2bf(y);
            }
        }
    }
}

// ---------------------------------------------------------------------------
// Attention on fused qkv buffer [NTOK][1536] (q|k|v). Block = (b,h,64 q rows).
// ---------------------------------------------------------------------------
__global__ __launch_bounds__(256) void attn_kernel(
    const u16* __restrict__ qkv, u16* __restrict__ o)
{
    __shared__ __align__(16) u16 kvs[S_ * HD_];      // 32 KB: K rows, then V^T
    __shared__ __align__(16) u16 P[4 * 16 * S_];     // 32 KB: per-wave probs
    int bx = blockIdx.x;
    int qc = bx & 3;
    int h = (bx >> 2) & 7;
    int b = bx >> 5;
    int t = threadIdx.x;
    int lane = t & 63, w = t >> 6;
    int l15 = lane & 15, quad = lane >> 4;
    size_t rowb = (size_t)b * S_;

    // stage K: thread t loads K row s=t (64 bf16)
    {
        const u16* src = qkv + (rowb + t) * QKV3 + D_ + h * HD_;
        #pragma unroll
        for (int j = 0; j < 8; j++)
            *(uint4*)&kvs[t * HD_ + j * 8] = *(const uint4*)(src + j * 8);
    }
    // load Q fragments (wave's 16 q rows)
    bf16x8 aQ[2];
    {
        int qrow = qc * 64 + w * 16 + l15;
        const u16* src = qkv + (rowb + qrow) * QKV3 + h * HD_ + quad * 8;
        aQ[0] = *(const bf16x8*)(src);
        aQ[1] = *(const bf16x8*)(src + 32);
    }
    __syncthreads();

    // phase 1: S = Q K^T  (wave computes 16 x 256)
    f32x4 sc[16];
    #pragma unroll
    for (int nc = 0; nc < 16; nc++) {
        f32x4 acc = {0.f, 0.f, 0.f, 0.f};
        bf16x8 b0 = *(const bf16x8*)&kvs[(nc * 16 + l15) * HD_ + quad * 8];
        bf16x8 b1 = *(const bf16x8*)&kvs[(nc * 16 + l15) * HD_ + 32 + quad * 8];
        acc = __builtin_amdgcn_mfma_f32_16x16x32_bf16(aQ[0], b0, acc, 0, 0, 0);
        acc = __builtin_amdgcn_mfma_f32_16x16x32_bf16(aQ[1], b1, acc, 0, 0, 0);
        sc[nc] = acc;
    }
    const float scale = 0.125f;  // 1/sqrt(64)
    float rmax[4], rinv[4];
    #pragma unroll
    for (int r = 0; r < 4; r++) {
        float mx = -1e30f;
        #pragma unroll
        for (int nc = 0; nc < 16; nc++) mx = fmaxf(mx, sc[nc][r]);
        for (int off = 1; off < 16; off <<= 1) mx = fmaxf(mx, __shfl_xor(mx, off));
        rmax[r] = mx * scale;
    }
    #pragma unroll
    for (int r = 0; r < 4; r++) {
        float sum = 0.f;
        #pragma unroll
        for (int nc = 0; nc < 16; nc++) {
            float p = __expf(sc[nc][r] * scale - rmax[r]);
            sc[nc][r] = p;
            sum += p;
        }
        for (int off = 1; off < 16; off <<= 1) sum += __shfl_xor(sum, off);
        rinv[r] = 1.0f / sum;
    }
    #pragma unroll
    for (int nc = 0; nc < 16; nc++)
        #pragma unroll
        for (int r = 0; r < 4; r++)
            P[w * 16 * S_ + (quad * 4 + r) * S_ + nc * 16 + l15] =
                f2bf(sc[nc][r] * rinv[r]);
    __syncthreads();  // all waves done with K region + P written

    // stage V^T[64][256] into kvs
    {
        const u16* src = qkv + (rowb + t) * QKV3 + 2 * D_ + h * HD_;
        #pragma unroll
        for (int dj = 0; dj < 8; dj++) {
            uint4 x = *(const uint4*)(src + dj * 8);
            const u16* xs = (const u16*)&x;
            #pragma unroll
            for (int i = 0; i < 8; i++) kvs[(dj * 8 + i) * S_ + t] = xs[i];
        }
    }
    __syncthreads();

    // phase 2: O = P @ V   (wave: 16 x 64)
    f32x4 accO[4];
    f32x4 zero = {0.f, 0.f, 0.f, 0.f};
    #pragma unroll
    for (int nt = 0; nt < 4; nt++) accO[nt] = zero;
    for (int ks = 0; ks < 8; ks++) {
        bf16x8 aP = *(const bf16x8*)&P[w * 16 * S_ + l15 * S_ + ks * 32 + quad * 8];
        #pragma unroll
        for (int nt = 0; nt < 4; nt++) {
            bf16x8 bV = *(const bf16x8*)&kvs[(nt * 16 + l15) * S_ + ks * 32 + quad * 8];
            accO[nt] = __builtin_amdgcn_mfma_f32_16x16x32_bf16(aP, bV, accO[nt], 0, 0, 0);
        }
    }
    #pragma unroll
    for (int nt = 0; nt < 4; nt++)
        #pragma unroll
        for (int r = 0; r < 4; r++) {
            int orow = qc * 64 + w * 16 + quad * 4 + r;
            o[(rowb + orow) * D_ + h * HD_ + nt * 16 + l15] = f2bf(accO[nt][r]);
        }
}

// ---------------------------------------------------------------------------
// LayerNorm: out = LN(in [+ res]) * g + b, optional GELU, optional +PE.
// in fp32 [M][WIDTH], res bf16 (or null), out bf16. One row per block.
// ---------------------------------------------------------------------------
template <int WIDTH, bool RES, bool GELU, bool PE>
__global__ __launch_bounds__(WIDTH) void ln_kernel(
    const float* __restrict__ in, const u16* __restrict__ res,
    const float* __restrict__ g, const float* __restrict__ b,
    u16* __restrict__ out)
{
    __shared__ float rs[8], rq[8];
    int row = blockIdx.x;
    int t = threadIdx.x;
    size_t base = (size_t)row * WIDTH;
    float v = in[base + t];
    if (RES) v += bf2f(res[base + t]);
    float sm = v, sq = v * v;
    for (int off = 32; off; off >>= 1) {
        sm += __shfl_xor(sm, off);
        sq += __shfl_xor(sq, off);
    }
    constexpr int NW = WIDTH / 64;
    if ((t & 63) == 0) { rs[t >> 6] = sm; rq[t >> 6] = sq; }
    __syncthreads();
    float ts = 0.f, tq = 0.f;
    #pragma unroll
    for (int i = 0; i < NW; i++) { ts += rs[i]; tq += rq[i]; }
    float mean = ts / (float)WIDTH;
    float var = tq / (float)WIDTH - mean * mean;
    float rstd = rsqrtf(var + 1e-5f);
    float y = (v - mean) * rstd * g[t] + b[t];
    if (GELU) y = gelu_f(y);
    if (PE) {
        const float c = -9.210340371976184f / (float)D_;  // -ln(10000)/D
        int s = row & (S_ - 1);
        int i2 = t >> 1;
        float ang = (float)s * __expf((float)(2 * i2) * c);
        y += (t & 1) ? __cosf(ang) : __sinf(ang);
    }
    out[base + t] = f2bf(y);
}

// ---------------------------------------------------------------------------
// Head: out = tanh(y2 @ Wp3 + bp3) * scale + bias. 8 rows x 32 cols per block.
// ---------------------------------------------------------------------------
__global__ __launch_bounds__(256) void head_kernel(
    const u16* __restrict__ y2, const float* __restrict__ W,
    const float* __restrict__ bias, const float* __restrict__ scl,
    const float* __restrict__ bs, float* __restrict__ out)
{
    __shared__ float Ws[128 * ACT_];
    __shared__ u16 Ys[8 * 128];
    int t = threadIdx.x;
    for (int i = t; i < 128 * ACT_; i += 256) Ws[i] = W[i];
    int r0 = blockIdx.x * 8;
    for (int i = t; i < 8 * 128; i += 256) Ys[i] = y2[(size_t)r0 * 128 + i];
    __syncthreads();
    int lr = t >> 5, c = t & 31;
    if (c < ACT_) {
        float acc = bias[c];
        for (int kk = 0; kk < 128; kk++)
            acc += bf2f(Ys[lr * 128 + kk]) * Ws[kk * ACT_ + c];
        float y = tanhf(acc);
        out[(size_t)(r0 + lr) * ACT_ + c] = y * scl[c] + bs[c];
    }
}

// ---------------------------------------------------------------------------
extern "C" void kernel_launch(void* const* d_in, const int* in_sizes, int n_in,
                              void* d_out, int out_size, void* d_ws, size_t ws_size,
                              hipStream_t stream)
{
    const float* obs   = (const float*)d_in[0];
    const float* W_in  = (const float*)d_in[1];
    const float* b_in  = (const float*)d_in[2];
    const float* g_in  = (const float*)d_in[3];
    const float* be_in = (const float*)d_in[4];
    const float* Wq  = (const float*)d_in[5];
    const float* bq  = (const float*)d_in[6];
    const float* Wk  = (const float*)d_in[7];
    const float* bk  = (const float*)d_in[8];
    const float* Wv  = (const float*)d_in[9];
    const float* bv  = (const float*)d_in[10];
    const float* Wo  = (const float*)d_in[11];
    const float* bo  = (const float*)d_in[12];
    const float* g1  = (const float*)d_in[13];
    const float* be1 = (const float*)d_in[14];
    const float* W1  = (const float*)d_in[15];
    const float* b1  = (const float*)d_in[16];
    const float* W2  = (const float*)d_in[17];
    const float* b2  = (const float*)d_in[18];
    const float* g2  = (const float*)d_in[19];
    const float* be2 = (const float*)d_in[20];
    const float* Wp1  = (const float*)d_in[21];
    const float* bp1  = (const float*)d_in[22];
    const float* gp1  = (const float*)d_in[23];
    const float* bep1 = (const float*)d_in[24];
    const float* Wp2  = (const float*)d_in[25];
    const float* bp2  = (const float*)d_in[26];
    const float* gp2  = (const float*)d_in[27];
    const float* bep2 = (const float*)d_in[28];
    const float* Wp3  = (const float*)d_in[29];
    const float* bp3  = (const float*)d_in[30];
    const float* ascl = (const float*)d_in[31];
    const float* abias = (const float*)d_in[32];

    char* ws = (char*)d_ws;
    size_t off = 0;
    auto alloc = [&](size_t bytes) {
        void* p = ws + off;
        off += (bytes + 255) & ~(size_t)255;
        return p;
    };
    u16* WQKVT = (u16*)alloc((size_t)L_ * QKV3 * D_ * 2);     // 12 MB
    u16* WOT   = (u16*)alloc((size_t)L_ * D_ * D_ * 2);       // 4 MB
    u16* W1T   = (u16*)alloc((size_t)L_ * D_ * FF_ * 2);      // 16 MB
    u16* W2T   = (u16*)alloc((size_t)L_ * FF_ * D_ * 2);      // 16 MB
    u16* WP1T  = (u16*)alloc((size_t)D_ * (D_ / 2) * 2);
    u16* WP2T  = (u16*)alloc((size_t)(D_ / 2) * (D_ / 4) * 2);
    u16* WINT  = (u16*)alloc((size_t)OBS_ * D_ * 2);
    float* bqkv = (float*)alloc((size_t)L_ * QKV3 * 4);
    u16* x_bf = (u16*)alloc((size_t)NTOK * D_ * 2);           // 16 MB
    float* tmp = (float*)alloc((size_t)NTOK * D_ * 4);        // 32 MB, multi-use
    char* regionA = (char*)alloc((size_t)NTOK * FF_ * 2);     // 64 MB
    (void)ws_size; (void)in_sizes; (void)n_in; (void)out_size; (void)WINT;

    u16* qkvbuf = (u16*)(regionA);                            // 48 MB
    u16* obuf = (u16*)(regionA + (size_t)NTOK * QKV3 * 2);    // 16 MB
    u16* hbuf = (u16*)(regionA);                              // 64 MB (aliases)
    // head-stage aliases inside tmp (32 MB)
    char* tmpB = (char*)tmp;
    float* p1out = tmp;                              // [NTOK][256] f32, 16 MB
    u16* y1_bf = (u16*)(tmpB + (16u << 20));         // 8 MB
    float* p2out = (float*)(tmpB + (24u << 20));     // [NTOK][128] f32, 8 MB
    u16* y2_bf = (u16*)(tmpB);                       // 4 MB (p1out dead)

    dim3 tb(32, 8);
    size_t DD = (size_t)D_ * D_;
    transpose_bf16_kernel<<<dim3(16, 16, L_), tb, 0, stream>>>(
        Wq, WQKVT, D_, D_, DD, (size_t)QKV3 * D_);
    transpose_bf16_kernel<<<dim3(16, 16, L_), tb, 0, stream>>>(
        Wk, WQKVT + DD, D_, D_, DD, (size_t)QKV3 * D_);
    transpose_bf16_kernel<<<dim3(16, 16, L_), tb, 0, stream>>>(
        Wv, WQKVT + 2 * DD, D_, D_, DD, (size_t)QKV3 * D_);
    transpose_bf16_kernel<<<dim3(16, 16, L_), tb, 0, stream>>>(
        Wo, WOT, D_, D_, DD, DD);
    transpose_bf16_kernel<<<dim3(64, 16, L_), tb, 0, stream>>>(
        W1, W1T, D_, FF_, (size_t)D_ * FF_, (size_t)D_ * FF_);
    transpose_bf16_kernel<<<dim3(16, 64, L_), tb, 0, stream>>>(
        W2, W2T, FF_, D_, (size_t)D_ * FF_, (size_t)D_ * FF_);
    transpose_bf16_kernel<<<dim3(8, 16, 1), tb, 0, stream>>>(
        Wp1, WP1T, D_, D_ / 2, 0, 0);
    transpose_bf16_kernel<<<dim3(4, 8, 1), tb, 0, stream>>>(
        Wp2, WP2T, D_ / 2, D_ / 4, 0, 0);
    concat_bias_kernel<<<L_ * QKV3 / 256, 256, 0, stream>>>(bq, bk, bv, bqkv);

    // input projection (fp32 GEMM) + LN + GELU + positional encoding
    in_gemm_kernel<<<dim3(D_ / 64, NTOK / 64), 256, 0, stream>>>(
        obs, W_in, b_in, tmp);
    ln_kernel<D_, false, true, true><<<NTOK, D_, 0, stream>>>(
        tmp, nullptr, g_in, be_in, x_bf);

    const int MG = NTOK / 128;  // 128
    for (int l = 0; l < L_; l++) {
        const u16* wqkvt = WQKVT + (size_t)l * QKV3 * D_;
        const u16* wot = WOT + (size_t)l * DD;
        const u16* w1t = W1T + (size_t)l * D_ * FF_;
        const u16* w2t = W2T + (size_t)l * FF_ * D_;

        gemm_bt_kernel<0><<<dim3(QKV3 / 128, MG), 256, 0, stream>>>(
            x_bf, wqkvt, bqkv + l * QKV3, qkvbuf, NTOK, QKV3, D_);
        attn_kernel<<<B_ * H_ * (S_ / 64), 256, 0, stream>>>(qkvbuf, obuf);
        gemm_bt_kernel<2><<<dim3(D_ / 128, MG), 256, 0, stream>>>(
            obuf, wot, bo + l * D_, tmp, NTOK, D_, D_);
        ln_kernel<D_, true, false, false><<<NTOK, D_, 0, stream>>>(
            tmp, x_bf, g1 + l * D_, be1 + l * D_, x_bf);
        gemm_bt_kernel<1><<<dim3(FF_ / 128, MG), 256, 0, stream>>>(
            x_bf, w1t, b1 + l * FF_, hbuf, NTOK, FF_, D_);
        gemm_bt_kernel<2><<<dim3(D_ / 128, MG), 256, 0, stream>>>(
            hbuf, w2t, b2 + l * D_, tmp, NTOK, D_, FF_);
        ln_kernel<D_, true, false, false><<<NTOK, D_, 0, stream>>>(
            tmp, x_bf, g2 + l * D_, be2 + l * D_, x_bf);
    }

    // policy head
    gemm_bt_kernel<2><<<dim3((D_ / 2) / 128, MG), 256, 0, stream>>>(
        x_bf, WP1T, bp1, p1out, NTOK, D_ / 2, D_);
    ln_kernel<D_ / 2, false, true, false><<<NTOK, D_ / 2, 0, stream>>>(
        p1out, nullptr, gp1, bep1, y1_bf);
    gemm_bt_kernel<2><<<dim3((D_ / 4) / 128, MG), 256, 0, stream>>>(
        y1_bf, WP2T, bp2, p2out, NTOK, D_ / 4, D_ / 2);
    ln_kernel<D_ / 4, false, true, false><<<NTOK, D_ / 4, 0, stream>>>(
        p2out, nullptr, gp2, bep2, y2_bf);
    head_kernel<<<NTOK / 8, 256, 0, stream>>>(
        y2_bf, Wp3, bp3, ascl, abias, (float*)d_out);
}